// Round 9
// baseline (1180.203 us; speedup 1.0000x reference)
//
#include <hip/hip_runtime.h>
#include <math.h>

typedef __attribute__((ext_vector_type(8))) short short8;
typedef __attribute__((ext_vector_type(4))) float f32x4;

__device__ inline unsigned short f2bf(float f) {
  unsigned u = __float_as_uint(f);
  u = (u + 0x7fffu + ((u >> 16) & 1u)) >> 16;
  return (unsigned short)u;
}

// async global->LDS (gfx950). LDS dst is wave-uniform; lane l writes dst+l*size.
// Global src IS per-lane (m173) -> source-swizzled staging into halo layouts.
__device__ inline void async4(const float* g, float* l) {
  __builtin_amdgcn_global_load_lds(
      (const __attribute__((address_space(1))) void*)g,
      (__attribute__((address_space(3))) void*)l, 4, 0, 0);
}

// ---------------------------------------------------------------------------
// conv1: 4x4 s=2 p=1 ReLU, CIN=1, 128x128 -> 64x64, 32 ch. Single barrier.
// ---------------------------------------------------------------------------
__global__ __launch_bounds__(256, 4)
void conv1_lds(const float* __restrict__ x, const float* __restrict__ w,
               const float* __restrict__ bias, float* __restrict__ out) {
  int bid = blockIdx.x;
  int cchunk = bid & 1;
  int t4 = (bid >> 1) & 3;
  int n = bid >> 3;
  int co0 = cchunk * 16;
  int y0 = t4 * 16;
  int yi0 = 2 * y0 - 1;

  __shared__ float xs[34 * 128];
  __shared__ float wl[16][16];

  int t = threadIdx.x;
  for (int idx = t; idx < 34 * 128; idx += 256) {
    int gy = yi0 + (idx >> 7);
    int gx = idx & 127;
    bool ok = (unsigned)gy < 128;
    xs[idx] = ok ? x[(size_t)n * 16384 + gy * 128 + gx] : 0.f;
  }
  {
    int cc = t & 15;
    int tap = t >> 4;
    if (t < 256) wl[tap][cc] = w[(size_t)(co0 + cc) * 16 + tap];
  }
  __syncthreads();

  int sx = t & 63;
  int rg = t >> 6;

  float acc[4][16];
#pragma unroll
  for (int j = 0; j < 4; j++)
#pragma unroll
    for (int c = 0; c < 16; c++) acc[j][c] = 0.f;

  int ix0 = 2 * sx - 1;
#pragma unroll
  for (int ky = 0; ky < 4; ky++) {
#pragma unroll
    for (int kx = 0; kx < 4; kx++) {
      int ix = ix0 + kx;
      bool xok = (unsigned)ix < 128;
      float xv[4];
#pragma unroll
      for (int j = 0; j < 4; j++) {
        int lrow = 2 * (4 * rg + j) + ky;
        float v = xs[lrow * 128 + (xok ? ix : 0)];
        xv[j] = xok ? v : 0.f;
      }
      const float* wr = &wl[ky * 4 + kx][0];
#pragma unroll
      for (int c = 0; c < 16; c += 4) {
        float4 wv = *(const float4*)(wr + c);
#pragma unroll
        for (int j = 0; j < 4; j++) {
          acc[j][c + 0] = fmaf(xv[j], wv.x, acc[j][c + 0]);
          acc[j][c + 1] = fmaf(xv[j], wv.y, acc[j][c + 1]);
          acc[j][c + 2] = fmaf(xv[j], wv.z, acc[j][c + 2]);
          acc[j][c + 3] = fmaf(xv[j], wv.w, acc[j][c + 3]);
        }
      }
    }
  }

#pragma unroll
  for (int j = 0; j < 4; j++) {
    int oy = y0 + 4 * rg + j;
    float* op = out + (((size_t)n * 32 + co0) * 64 + oy) * 64 + sx;
#pragma unroll
    for (int c = 0; c < 16; c++) {
      float v = acc[j][c] + bias[co0 + c];
      op[(size_t)c * 4096] = fmaxf(v, 0.f);
    }
  }
}

// ---------------------------------------------------------------------------
// conv2: r6's proven parity-split halo version (unchanged).
// ---------------------------------------------------------------------------
template<int CIN, int COUT, int CCH>
__global__ __launch_bounds__(256, 4)
void conv4x4s2_p(const float* __restrict__ x, const float* __restrict__ w,
                 const float* __restrict__ bias, float* __restrict__ out) {
  constexpr int NCH = COUT / CCH;
  int bid = blockIdx.x;
  int cchunk = bid % NCH;
  int n = bid / NCH;
  int co0 = cchunk * CCH;

  __shared__ float xs[66 * 68];   // rows 0..65 = iy+1; parity-split cols
  __shared__ float wl[16][CCH];

  int t = threadIdx.x;
  int sx = t & 31;
  int sy0 = t >> 5;

  for (int i = t; i < 66 * 68; i += 256) xs[i] = 0.f;

  float acc[4][CCH];
#pragma unroll
  for (int j = 0; j < 4; j++)
#pragma unroll
    for (int c = 0; c < CCH; c++) acc[j][c] = 0.f;

  const float* xn = x + (size_t)n * CIN * 4096;

  for (int ci = 0; ci < CIN; ci++) {
    __syncthreads();
#pragma unroll
    for (int k = 0; k < 4; k++) {
      int idx = k * 1024 + t * 4;
      int row = idx >> 6;
      int col = idx & 63;        // even
      float4 v = *(const float4*)(xn + (size_t)ci * 4096 + idx);
      float* rp = xs + (row + 1) * 68;
      int h = col >> 1;
      rp[34 + h]     = v.x;      // tc = col+1 (odd)
      rp[h + 1]      = v.y;      // tc = col+2 (even)
      rp[34 + h + 1] = v.z;      // tc = col+3 (odd)
      rp[h + 2]      = v.w;      // tc = col+4 (even)
    }
    {
      int cc = t & (CCH - 1);
      int tap = t >> 4;          // CCH==16
      if (tap < 16) wl[tap][cc] = w[(size_t)(co0 + cc) * (CIN * 16) + ci * 16 + tap];
    }
    __syncthreads();

#pragma unroll
    for (int ky = 0; ky < 4; ky++) {
#pragma unroll
      for (int kx = 0; kx < 4; kx++) {
        int pc = ((kx & 1) ? 34 : 0) + sx + (kx >> 1);
        float xv[4];
#pragma unroll
        for (int j = 0; j < 4; j++) {
          int row = 2 * (sy0 + j * 8) + ky;   // iy+1, in [0,65]
          xv[j] = xs[row * 68 + pc];
        }
        const float* wr = &wl[ky * 4 + kx][0];
#pragma unroll
        for (int c = 0; c < CCH; c += 4) {
          float4 wv = *(const float4*)(wr + c);
#pragma unroll
          for (int j = 0; j < 4; j++) {
            acc[j][c + 0] = fmaf(xv[j], wv.x, acc[j][c + 0]);
            acc[j][c + 1] = fmaf(xv[j], wv.y, acc[j][c + 1]);
            acc[j][c + 2] = fmaf(xv[j], wv.z, acc[j][c + 2]);
            acc[j][c + 3] = fmaf(xv[j], wv.w, acc[j][c + 3]);
          }
        }
      }
    }
  }

#pragma unroll
  for (int j = 0; j < 4; j++) {
    int sy = sy0 + j * 8;
    float* op = out + (((size_t)n * COUT + co0) * 32 + sy) * 32 + sx;
#pragma unroll
    for (int c = 0; c < CCH; c++) {
      float v = acc[j][c] + bias[co0 + c];
      v = fmaxf(v, 0.f);
      op[(size_t)c * 1024] = v;
    }
  }
}

// ---------------------------------------------------------------------------
// Prepack conv3 weights for LDS-linear async staging:
// ew3 [co=64][ci=64*9] -> We3p [cg=16][cch=4][row=36][cc=16]
// (row = c4*9 + kk; per-(cg,cch) block is 576 contiguous floats).
// ---------------------------------------------------------------------------
__global__ void wprep_enc3p(const float* __restrict__ w, float* __restrict__ wt) {
  int i = blockIdx.x * 256 + threadIdx.x;
  if (i < 36864) {
    int cc = i & 15;
    int row = (i >> 4) % 36;
    int blk = i / 576;         // cg*4 + cch
    int cch = blk & 3;
    int cg = blk >> 2;
    int c4 = row / 9, kk = row % 9;
    wt[i] = w[(size_t)(cch * 16 + cc) * (64 * 9) + (cg * 4 + c4) * 9 + kk];
  }
}

// ---------------------------------------------------------------------------
// conv3 ah: 3x3 s=1 p=1 ReLU on 32x32, CIN=64 (ENCODER - fp32 bit-exact,
// feeds z -> argmin). Compute core = r6's PROVEN conv3x3_r8 (halo planes,
// no selects, acc[8][8], fmaf chain cg -> c4 -> ky -> kx unchanged).
// Staging = async global_load_lds with SOURCE-swizzled per-lane addresses
// (m173 pattern): LDS linear dst, each lane's global src is either the
// interior x element or a global zero word (halo/pad) -> halo cells are
// rewritten with exact zeros every cg. Plane padded to 1216 = 19x64, so
// wave wv stages plane wv in 19 async4 calls. Double-buffered, ONE
// barrier per cg; ~22 loads/wave in flight under 2304 FMAs.
// (256,3): 170-VGPR budget (r8's spill was the 128 budget + guarded
// selects; both removed here).
// ---------------------------------------------------------------------------
template<int CIN, int COUT>
__global__ __launch_bounds__(256, 3)
void conv3x3_ah(const float* __restrict__ x, const float* __restrict__ wp,
                const float* __restrict__ zsrc, const float* __restrict__ bias,
                float* __restrict__ out) {
  constexpr int NCH = COUT / 16;   // 4
  int bid = blockIdx.x;
  int cchunk = bid % NCH;
  int n = bid / NCH;
  int co0 = cchunk * 16;

  __shared__ float xs[2][4][1216];   // halo planes, row stride 34, 19x64 pad
  __shared__ float wl[2][36][16];

  int t = threadIdx.x;
  int lane = t & 63;
  int wv = t >> 6;           // wave 0..3 (stages plane wv)
  int sx = t & 31;
  int rg = (t >> 5) & 3;     // 4 row groups x 8 rows
  int cob = (t >> 7) * 8;    // 8-co half

  const float* xn = x + (size_t)n * CIN * 1024;

  float acc[8][8];
#pragma unroll
  for (int j = 0; j < 8; j++)
#pragma unroll
    for (int c = 0; c < 8; c++) acc[j][c] = 0.f;

  // ---- async stage of one cg: per-lane source-swizzled halo fill
  auto stage = [&](int buf, int cg) {
    const float* xplane = xn + (size_t)(cg * 4 + wv) * 1024;
    float* db = &xs[buf][wv][0];
#pragma unroll
    for (int i = 0; i < 19; i++) {
      int o = i * 64 + lane;           // linear offset in padded plane
      int row = o / 34;                // 0..35 (34,35 = pad)
      int col = o - row * 34;          // 0..33
      bool valid = ((unsigned)(row - 1) < 32u) && ((unsigned)(col - 1) < 32u);
      const float* g = valid ? (xplane + (row - 1) * 32 + (col - 1)) : zsrc;
      async4(g, db + i * 64);
    }
    const float* wsrc = wp + (size_t)(cg * NCH + cchunk) * 576;
    float* wb = &wl[buf][0][0];
#pragma unroll
    for (int c = 0; c < 3; c++) {
      int ck = wv + c * 4;             // 9 chunks x 64 floats
      if (ck < 9) async4(wsrc + ck * 64 + lane, wb + ck * 64);
    }
  };

  stage(0, 0);
  __syncthreads();

  int cur = 0;
  for (int cg = 0; cg < CIN / 4; cg++) {
    if (cg + 1 < CIN / 4) stage(cur ^ 1, cg + 1);

#pragma unroll
    for (int c4 = 0; c4 < 4; c4++) {
      const float* xc = &xs[cur][c4][0];
      float xv[10][3];
#pragma unroll
      for (int r = 0; r < 10; r++) {
#pragma unroll
        for (int cx = 0; cx < 3; cx++)
          xv[r][cx] = xc[(8 * rg + r) * 34 + sx + cx];  // halo handles bounds
      }
#pragma unroll
      for (int ky = 0; ky < 3; ky++) {
#pragma unroll
        for (int kx = 0; kx < 3; kx++) {
          const float* wr = &wl[cur][c4 * 9 + ky * 3 + kx][cob];
          float4 w0 = *(const float4*)(wr);
          float4 w1 = *(const float4*)(wr + 4);
#pragma unroll
          for (int j = 0; j < 8; j++) {
            float xx = xv[j + ky][kx];
            acc[j][0] = fmaf(xx, w0.x, acc[j][0]);
            acc[j][1] = fmaf(xx, w0.y, acc[j][1]);
            acc[j][2] = fmaf(xx, w0.z, acc[j][2]);
            acc[j][3] = fmaf(xx, w0.w, acc[j][3]);
            acc[j][4] = fmaf(xx, w1.x, acc[j][4]);
            acc[j][5] = fmaf(xx, w1.y, acc[j][5]);
            acc[j][6] = fmaf(xx, w1.z, acc[j][6]);
            acc[j][7] = fmaf(xx, w1.w, acc[j][7]);
          }
        }
      }
    }
    __syncthreads();   // drains async loads; next buffer ready
    cur ^= 1;
  }

#pragma unroll
  for (int j = 0; j < 8; j++) {
    int sy = 8 * rg + j;
    float* op = out + (((size_t)n * COUT + co0 + cob) * 32 + sy) * 32 + sx;
#pragma unroll
    for (int c = 0; c < 8; c++) {
      float v = acc[j][c] + bias[co0 + cob + c];
      v = fmaxf(v, 0.f);
      op[(size_t)c * 1024] = v;
    }
  }
}

// ---------------------------------------------------------------------------
// Weight prep for MFMA dect1: tw1 [ci=64][co=32][4][4] fp32 ->
// Bws bf16 [par=4][tap=4][co=32][ci=64].
// ---------------------------------------------------------------------------
__global__ void wprep_dect1(const float* __restrict__ tw1,
                            unsigned short* __restrict__ Bws) {
  int i = blockIdx.x * 256 + threadIdx.x;
  if (i < 32768) {
    int ci = i & 63;
    int co = (i >> 6) & 31;
    int tap = (i >> 11) & 3;
    int par = i >> 13;
    int py = par >> 1, px = par & 1;
    int ky0 = (py + 1) & 1, kx0 = (px + 1) & 1;
    int kyi = tap >> 1, kxi = tap & 1;
    int ky = ky0 + 2 * kyi, kx = kx0 + 2 * kxi;
    Bws[i] = f2bf(tw1[(((size_t)ci * 32 + co) * 4 + ky) * 4 + kx]);
  }
}

// ---------------------------------------------------------------------------
// Weight prep for MFMA dec1: dw1 [co=64][ci=32][3][3] fp32 ->
// Wd1 bf16 [co][tap=9][ci=32]  (row stride 288 shorts = 576B, 16B-aligned).
// ---------------------------------------------------------------------------
__global__ void wprep_dec1(const float* __restrict__ dw1,
                           unsigned short* __restrict__ Wd1) {
  int i = blockIdx.x * 256 + threadIdx.x;
  if (i < 18432) {
    int ci = i & 31;
    int tap = (i >> 5) % 9;
    int co = i / 288;
    Wd1[i] = f2bf(dw1[(size_t)(co * 32 + ci) * 9 + tap]);
  }
}

// ---------------------------------------------------------------------------
// dec1 via MFMA (bf16 in, fp32 acc): 3x3 s=1 p=1 ReLU,
// qz [smp][32ci][32][32] fp32 -> d1 [smp][64co][32][32] fp32.
// ---------------------------------------------------------------------------
__global__ __launch_bounds__(256, 4)
void dec1_mfma(const float* __restrict__ qz,
               const unsigned short* __restrict__ Wd1,
               const float* __restrict__ bias, float* __restrict__ d1) {
  int strip = blockIdx.x & 3;
  int smp = blockIdx.x >> 2;
  int y0 = strip * 8;

  __shared__ __align__(16) unsigned short xt[10 * 34 * 32];

  int t = threadIdx.x;
  // stage rows y0-1..y0+8, cols -1..32, 32 ci (bf16 pairs)
  for (int idx = t; idx < 16 * 10 * 34; idx += 256) {
    int cc = idx % 34;
    int tmp = idx / 34;
    int rr = tmp % 10;
    int pp = tmp / 10;                 // ci pair 0..15
    int gy = y0 - 1 + rr;
    int gx = cc - 1;
    bool ok = ((unsigned)gy < 32) && ((unsigned)gx < 32);
    const float* p = qz + ((size_t)smp * 32 + 2 * pp) * 1024 + gy * 32 + gx;
    float v0 = ok ? p[0] : 0.f;
    float v1 = ok ? p[1024] : 0.f;
    unsigned pk = (unsigned)f2bf(v0) | ((unsigned)f2bf(v1) << 16);
    *(unsigned*)(&xt[(rr * 34 + cc) * 32 + 2 * pp]) = pk;
  }

  int lane = t & 63;
  int wv = t >> 6;                    // co-tile 0..3
  int mlo = lane & 15;
  int khi = lane >> 4;

  // A-frags: weights for co = wv*16+mlo, all 9 taps (global, L2-hot)
  short8 afr[9];
#pragma unroll
  for (int tap = 0; tap < 9; tap++)
    afr[tap] = *(const short8*)(Wd1 + (size_t)(wv * 16 + mlo) * 288 +
                                tap * 32 + khi * 8);
  float bb[4];
#pragma unroll
  for (int r = 0; r < 4; r++) bb[r] = bias[wv * 16 + khi * 4 + r];

  __syncthreads();

  for (int pt = 0; pt < 16; pt++) {
    int rl = pt >> 1;                 // row in strip 0..7
    int chf = pt & 1;                 // col half
    f32x4 acc = {0.f, 0.f, 0.f, 0.f};
#pragma unroll
    for (int tap = 0; tap < 9; tap++) {
      int ky = tap / 3, kx = tap % 3;
      const unsigned short* bp =
          xt + (((rl + ky) * 34) + chf * 16 + mlo + kx) * 32 + khi * 8;
      short8 b = *(const short8*)bp;
      acc = __builtin_amdgcn_mfma_f32_16x16x32_bf16(afr[tap], b, acc, 0, 0, 0);
    }
    int gyo = y0 + rl;
    int gxo = chf * 16 + mlo;
#pragma unroll
    for (int r = 0; r < 4; r++) {
      int co = wv * 16 + khi * 4 + r;
      d1[(((size_t)smp * 64 + co) * 32 + gyo) * 32 + gxo] =
          fmaxf(acc[r] + bb[r], 0.f);
    }
  }
}

// ---------------------------------------------------------------------------
// dect1 via MFMA: tconv k=4 s=2 p=1 ReLU,
// d1 [smp][64ci][32][32] fp32 -> d2 [smp][32co][64][64] fp32.
// ---------------------------------------------------------------------------
__global__ __launch_bounds__(256, 4)
void convt_mfma(const float* __restrict__ d1,
                const unsigned short* __restrict__ Bws,
                const float* __restrict__ bias, float* __restrict__ d2) {
  constexpr int CP = 72;
  int bid = blockIdx.x;
  int rp = bid & 15;
  int smp = bid >> 4;

  __shared__ __align__(16) unsigned short xt[4 * 34 * CP];

  int t = threadIdx.x;

  for (int idx = t; idx < 32 * 4 * 34; idx += 256) {
    int cc = idx % 34;
    int tmp = idx / 34;
    int rr = tmp & 3;
    int pp = tmp >> 2;
    int gy = 2 * rp - 1 + rr;
    int gx = cc - 1;
    bool ok = ((unsigned)gy < 32) && ((unsigned)gx < 32);
    const float* p = d1 + ((size_t)smp * 64 + 2 * pp) * 1024 + gy * 32 + gx;
    float v0 = ok ? p[0] : 0.f;
    float v1 = ok ? p[1024] : 0.f;
    unsigned pk = (unsigned)f2bf(v0) | ((unsigned)f2bf(v1) << 16);
    *(unsigned*)(&xt[(rr * 34 + cc) * CP + 2 * pp]) = pk;
  }
  __syncthreads();

  int lane = t & 63;
  int wv = t >> 6;
  int row2 = wv >> 1;
  int c0 = (wv & 1) * 16;
  int mlo = lane & 15;
  int khi = lane >> 4;

  f32x4 acc[4][2];
#pragma unroll
  for (int par = 0; par < 4; par++)
#pragma unroll
    for (int nt = 0; nt < 2; nt++) {
      f32x4 z = {0.f, 0.f, 0.f, 0.f};
      acc[par][nt] = z;
    }

#pragma unroll
  for (int par = 0; par < 4; par++) {
    int py = par >> 1, px = par & 1;
    int ky0 = (py + 1) & 1, kx0 = (px + 1) & 1;
    int ay = (py + 1 - ky0) >> 1;
    int ax = (px + 1 - kx0) >> 1;
#pragma unroll
    for (int tap = 0; tap < 4; tap++) {
      int kyi = tap >> 1, kxi = tap & 1;
      int rrp = row2 + 1 + (ay - kyi);
      int ccb = c0 + 1 + (ax - kxi);
#pragma unroll
      for (int kc = 0; kc < 2; kc++) {
        const unsigned short* ap =
            xt + ((rrp * 34) + ccb + mlo) * CP + kc * 32 + khi * 8;
        short8 a = *(const short8*)ap;
#pragma unroll
        for (int nt = 0; nt < 2; nt++) {
          const unsigned short* bp =
              Bws + (((size_t)(par * 4 + tap) * 32 + nt * 16 + mlo) * 64) +
              kc * 32 + khi * 8;
          short8 b = *(const short8*)bp;
          acc[par][nt] =
              __builtin_amdgcn_mfma_f32_16x16x32_bf16(a, b, acc[par][nt], 0, 0, 0);
        }
      }
    }
  }

  int sy = 2 * rp + row2;
#pragma unroll
  for (int par = 0; par < 4; par++) {
    int py = par >> 1, px = par & 1;
    int oy = 2 * sy + py;
#pragma unroll
    for (int nt = 0; nt < 2; nt++) {
      int co = nt * 16 + mlo;
      float b = bias[co];
      float* op = d2 + (((size_t)smp * 32 + co) * 64 + oy) * 64;
#pragma unroll
      for (int r = 0; r < 4; r++) {
        int sx = c0 + khi * 4 + r;
        int ox = 2 * sx + px;
        op[ox] = fmaxf(acc[par][nt][r] + b, 0.f);
      }
    }
  }
}

// ---------------------------------------------------------------------------
// dect2: tconv k=4 s=2 p=1, CIN=32, COUT=1, sigmoid; all 4 parities per
// thread. CSTG=8. grid = NB * 4 row-tiles. 64x64 -> 128x128.
// ---------------------------------------------------------------------------
__global__ __launch_bounds__(256, 4)
void dect2_full(const float* __restrict__ x, const float* __restrict__ w,
                const float* __restrict__ bias, float* __restrict__ out) {
  int ptile = blockIdx.x & 3;
  int n = blockIdx.x >> 2;
  int y0 = ptile * 16;

  __shared__ float xs[8][1152];
  int t = threadIdx.x;
  int sx = t & 63;
  int r4 = t >> 6;

  float acc[4][4];
#pragma unroll
  for (int j = 0; j < 4; j++)
#pragma unroll
    for (int p = 0; p < 4; p++) acc[j][p] = 0.f;

  const float* xn = x + (size_t)n * 32 * 4096;

  for (int cg = 0; cg < 4; cg++) {
    __syncthreads();
    for (int idx = t; idx < 8 * 1152; idx += 256) {
      int ch = idx / 1152;
      int rem = idx % 1152;
      int iy = y0 - 1 + rem / 64;
      int ix = rem & 63;
      bool ok = (unsigned)iy < 64;
      xs[ch][rem] = ok ? xn[(size_t)(cg * 8 + ch) * 4096 + iy * 64 + ix] : 0.f;
    }
    __syncthreads();

#pragma unroll
    for (int c4 = 0; c4 < 8; c4++) {
      int ci = cg * 8 + c4;
      const float* xc = &xs[c4][0];
      float xv[6][3];
#pragma unroll
      for (int r = 0; r < 6; r++) {
        int srow = 4 * r4 + r;
#pragma unroll
        for (int cx = 0; cx < 3; cx++) {
          int ix = sx - 1 + cx;
          bool ok = (unsigned)ix < 64;
          float v = xc[ok ? srow * 64 + ix : 0];
          xv[r][cx] = ok ? v : 0.f;
        }
      }
      float w16[16];
#pragma unroll
      for (int q = 0; q < 4; q++) {
        float4 ww = *(const float4*)(w + ci * 16 + 4 * q);
        w16[4 * q + 0] = ww.x; w16[4 * q + 1] = ww.y;
        w16[4 * q + 2] = ww.z; w16[4 * q + 3] = ww.w;
      }
#pragma unroll
      for (int py = 0; py < 2; py++) {
#pragma unroll
        for (int px = 0; px < 2; px++) {
          int par = py * 2 + px;
          int ky0 = (py + 1) & 1, kx0 = (px + 1) & 1;
          int ay = (py + 1 - ky0) >> 1;
          int ax = (px + 1 - kx0) >> 1;
#pragma unroll
          for (int kyi = 0; kyi < 2; kyi++) {
#pragma unroll
            for (int kxi = 0; kxi < 2; kxi++) {
              float wv = w16[(ky0 + 2 * kyi) * 4 + (kx0 + 2 * kxi)];
#pragma unroll
              for (int j = 0; j < 4; j++) {
                float xx = xv[j + ay + 1 - kyi][ax + 1 - kxi];
                acc[j][par] = fmaf(xx, wv, acc[j][par]);
              }
            }
          }
        }
      }
    }
  }

  float b0 = bias[0];
#pragma unroll
  for (int j = 0; j < 4; j++) {
    int iy = y0 + 4 * r4 + j;
#pragma unroll
    for (int py = 0; py < 2; py++) {
      float v0 = acc[j][py * 2 + 0] + b0;
      float v1 = acc[j][py * 2 + 1] + b0;
      float2 o;
      o.x = 1.f / (1.f + expf(-v0));
      o.y = 1.f / (1.f + expf(-v1));
      int oy = 2 * iy + py;
      *(float2*)(out + (size_t)n * 16384 + oy * 128 + 2 * sx) = o;
    }
  }
}

// ---------------------------------------------------------------------------
__global__ void cbn_prep(const float* __restrict__ cb, float* __restrict__ cbn) {
#pragma clang fp contract(off)
  int k = blockIdx.x * 256 + threadIdx.x;
  if (k < 512) {
    float m[32];
#pragma unroll
    for (int d = 0; d < 32; d++) {
      float c = cb[k * 32 + d];
      m[d] = c * c;
    }
    float r[8];
#pragma unroll
    for (int j = 0; j < 8; j++)
      r[j] = ((m[j] + m[8 + j]) + m[16 + j]) + m[24 + j];
    cbn[k] = ((r[0] + r[1]) + (r[2] + r[3])) + ((r[4] + r[5]) + (r[6] + r[7]));
  }
}

// ---------------------------------------------------------------------------
// FUSED conv4 (1x1) + VQ (np-exact arithmetic; proven).
// ---------------------------------------------------------------------------
__global__ __launch_bounds__(256)
void vq_fused(const float* __restrict__ h3, const float* __restrict__ w4,
              const float* __restrict__ b4, const float* __restrict__ cb,
              const float* __restrict__ cbn, float* __restrict__ qz,
              float* __restrict__ loss) {
  __shared__ float wl[64][32];
  int tid = threadIdx.x;
  for (int i = tid; i < 2048; i += 256) {
    int co = i & 31;
    int ci = i >> 5;
    wl[ci][co] = w4[(size_t)co * 64 + ci];
  }
  __syncthreads();

  int n = blockIdx.x >> 2;
  int p = (blockIdx.x & 3) * 256 + tid;
  const float* hn = h3 + (size_t)n * 65536;

  float zv[32];
#pragma unroll
  for (int c = 0; c < 32; c++) zv[c] = 0.f;
  for (int ci = 0; ci < 64; ci++) {
    float xv = hn[(size_t)ci * 1024 + p];
#pragma unroll
    for (int c = 0; c < 32; c += 4) {
      float4 wv = *(const float4*)&wl[ci][c];
      zv[c + 0] = fmaf(xv, wv.x, zv[c + 0]);
      zv[c + 1] = fmaf(xv, wv.y, zv[c + 1]);
      zv[c + 2] = fmaf(xv, wv.z, zv[c + 2]);
      zv[c + 3] = fmaf(xv, wv.w, zv[c + 3]);
    }
  }
#pragma unroll
  for (int c = 0; c < 32; c++) zv[c] = zv[c] + b4[c];

  float zz;
  {
#pragma clang fp contract(off)
    float m[32];
#pragma unroll
    for (int d = 0; d < 32; d++) m[d] = zv[d] * zv[d];
    float r[8];
#pragma unroll
    for (int j = 0; j < 8; j++)
      r[j] = ((m[j] + m[8 + j]) + m[16 + j]) + m[24 + j];
    zz = ((r[0] + r[1]) + (r[2] + r[3])) + ((r[4] + r[5]) + (r[6] + r[7]));
  }

  float best = 3.4e38f;
  int bk = 0;
  for (int k4 = 0; k4 < 512; k4 += 4) {
    float4 cn = *(const float4*)(cbn + k4);
    float da[4];
#pragma unroll
    for (int u = 0; u < 4; u++) da[u] = 0.f;
#pragma unroll
    for (int d = 0; d < 32; d += 4) {
#pragma unroll
      for (int u = 0; u < 4; u++) {
        float4 c = *(const float4*)(cb + (size_t)(k4 + u) * 32 + d);
        float a = da[u];
        a = fmaf(zv[d + 0], c.x, a);
        a = fmaf(zv[d + 1], c.y, a);
        a = fmaf(zv[d + 2], c.z, a);
        a = fmaf(zv[d + 3], c.w, a);
        da[u] = a;
      }
    }
#pragma unroll
    for (int u = 0; u < 4; u++) {
      float cnu = (u == 0) ? cn.x : (u == 1) ? cn.y : (u == 2) ? cn.z : cn.w;
      float s;
      {
#pragma clang fp contract(off)
        s = (zz + cnu) - 2.f * da[u];
      }
      int k = k4 + u;
      if (s < best) { best = s; bk = k; }
    }
  }

  float lsum = 0.f;
  float* qn = qz + (size_t)n * 32768;
#pragma unroll
  for (int d = 0; d < 32; d += 4) {
#pragma clang fp contract(off)
    float4 q = *(const float4*)(cb + (size_t)bk * 32 + d);
    float e;
    e = q.x - zv[d + 0]; lsum = fmaf(e, e, lsum);
    e = q.y - zv[d + 1]; lsum = fmaf(e, e, lsum);
    e = q.z - zv[d + 2]; lsum = fmaf(e, e, lsum);
    e = q.w - zv[d + 3]; lsum = fmaf(e, e, lsum);
    qn[(size_t)(d + 0) * 1024 + p] = zv[d + 0] + (q.x - zv[d + 0]);
    qn[(size_t)(d + 1) * 1024 + p] = zv[d + 1] + (q.y - zv[d + 1]);
    qn[(size_t)(d + 2) * 1024 + p] = zv[d + 2] + (q.z - zv[d + 2]);
    qn[(size_t)(d + 3) * 1024 + p] = zv[d + 3] + (q.w - zv[d + 3]);
  }

#pragma unroll
  for (int off = 32; off; off >>= 1) lsum += __shfl_down(lsum, off, 64);
  if ((tid & 63) == 0) atomicAdd(loss, lsum);
}

__global__ void finalize_loss(const float* __restrict__ loss, float* __restrict__ out) {
  if (threadIdx.x == 0) {
    float m = loss[0] / 8388608.f;
    out[0] = m + 0.26f * m;
  }
}

// ---------------------------------------------------------------------------
// Workspace (floats): A = chunk*131072, B = chunk*65536, then tail:
// cbn 512, loss 1, pad 3 (ZEROED - serve as global zero source for conv3
// halo staging), Bws 32768 shorts (16384 fl), Wd1 18432 shorts (9216 fl),
// We3p 36864 fl.
// ---------------------------------------------------------------------------
extern "C" void kernel_launch(void* const* d_in, const int* in_sizes, int n_in,
                              void* d_out, int out_size, void* d_ws, size_t ws_size,
                              hipStream_t stream) {
  (void)in_sizes; (void)n_in; (void)out_size;
  const float* x   = (const float*)d_in[0];
  const float* ew1 = (const float*)d_in[1];
  const float* eb1 = (const float*)d_in[2];
  const float* ew2 = (const float*)d_in[3];
  const float* eb2 = (const float*)d_in[4];
  const float* ew3 = (const float*)d_in[5];
  const float* eb3 = (const float*)d_in[6];
  const float* ew4 = (const float*)d_in[7];
  const float* eb4 = (const float*)d_in[8];
  const float* cb  = (const float*)d_in[9];
  const float* dw1 = (const float*)d_in[10];
  const float* db1 = (const float*)d_in[11];
  const float* tw1 = (const float*)d_in[12];
  const float* tb1 = (const float*)d_in[13];
  const float* tw2 = (const float*)d_in[14];
  const float* tb2 = (const float*)d_in[15];
  float* out = (float*)d_out;

  auto need = [](size_t c) -> size_t {
    return (c * 196608 + 516 + 16384 + 9216 + 36864) * 4;
  };
  int nchunks = 4;
  if (ws_size >= need(256)) nchunks = 1;
  else if (ws_size >= need(128)) nchunks = 2;
  int chunk = 256 / nchunks;

  float* ws = (float*)d_ws;
  float* A = ws;
  float* B = A + (size_t)chunk * 131072;
  float* cbn = B + (size_t)chunk * 65536;
  float* lossacc = cbn + 512;
  unsigned short* Bws = (unsigned short*)(cbn + 516);          // 16B-aligned
  unsigned short* Wd1 = (unsigned short*)(cbn + 516 + 16384);  // 16B-aligned
  float* We3p = cbn + 516 + 16384 + 9216;                      // 16B-aligned
  const float* zsrc = lossacc + 1;                             // stays zero

  float* h1 = A;
  float* h2 = B;
  float* h3 = A;
  float* qz = A + (size_t)chunk * 98304;
  float* d1 = B;
  float* d2 = A;

  cbn_prep<<<2, 256, 0, stream>>>(cb, cbn);
  wprep_dect1<<<128, 256, 0, stream>>>(tw1, Bws);
  wprep_dec1<<<72, 256, 0, stream>>>(dw1, Wd1);
  wprep_enc3p<<<144, 256, 0, stream>>>(ew3, We3p);
  (void)hipMemsetAsync(lossacc, 0, 16, stream);  // loss + 3 zero pads (zsrc)

  for (int c = 0; c < nchunks; c++) {
    const float* xc = x + (size_t)c * chunk * 128 * 128;
    float* outc = out + (size_t)c * chunk * 128 * 128;

    conv1_lds<<<chunk * 8, 256, 0, stream>>>(xc, ew1, eb1, h1);
    conv4x4s2_p<32, 64, 16>
        <<<chunk * 4, 256, 0, stream>>>(h1, ew2, eb2, h2);
    conv3x3_ah<64, 64>
        <<<chunk * 4, 256, 0, stream>>>(h2, We3p, zsrc, eb3, h3);

    vq_fused<<<chunk * 4, 256, 0, stream>>>(h3, ew4, eb4, cb, cbn, qz, lossacc);

    dec1_mfma<<<chunk * 4, 256, 0, stream>>>(qz, Wd1, db1, d1);
    convt_mfma<<<chunk * 16, 256, 0, stream>>>(d1, Bws, tb1, d2);
    dect2_full<<<chunk * 4, 256, 0, stream>>>(d2, tw2, tb2, outc);
  }

  finalize_loss<<<1, 64, 0, stream>>>(lossacc, out + 4194304);
}

// Round 10
// 1030.851 us; speedup vs baseline: 1.1449x; 1.1449x over previous
//
#include <hip/hip_runtime.h>
#include <math.h>

typedef __attribute__((ext_vector_type(8))) short short8;
typedef __attribute__((ext_vector_type(4))) float f32x4;

__device__ inline unsigned short f2bf(float f) {
  unsigned u = __float_as_uint(f);
  u = (u + 0x7fffu + ((u >> 16) & 1u)) >> 16;
  return (unsigned short)u;
}

// ---------------------------------------------------------------------------
// conv1: 4x4 s=2 p=1 ReLU, CIN=1, 128x128 -> 64x64, 32 ch. Single barrier.
// ---------------------------------------------------------------------------
__global__ __launch_bounds__(256, 4)
void conv1_lds(const float* __restrict__ x, const float* __restrict__ w,
               const float* __restrict__ bias, float* __restrict__ out) {
  int bid = blockIdx.x;
  int cchunk = bid & 1;
  int t4 = (bid >> 1) & 3;
  int n = bid >> 3;
  int co0 = cchunk * 16;
  int y0 = t4 * 16;
  int yi0 = 2 * y0 - 1;

  __shared__ float xs[34 * 128];
  __shared__ float wl[16][16];

  int t = threadIdx.x;
  for (int idx = t; idx < 34 * 128; idx += 256) {
    int gy = yi0 + (idx >> 7);
    int gx = idx & 127;
    bool ok = (unsigned)gy < 128;
    xs[idx] = ok ? x[(size_t)n * 16384 + gy * 128 + gx] : 0.f;
  }
  {
    int cc = t & 15;
    int tap = t >> 4;
    if (t < 256) wl[tap][cc] = w[(size_t)(co0 + cc) * 16 + tap];
  }
  __syncthreads();

  int sx = t & 63;
  int rg = t >> 6;

  float acc[4][16];
#pragma unroll
  for (int j = 0; j < 4; j++)
#pragma unroll
    for (int c = 0; c < 16; c++) acc[j][c] = 0.f;

  int ix0 = 2 * sx - 1;
#pragma unroll
  for (int ky = 0; ky < 4; ky++) {
#pragma unroll
    for (int kx = 0; kx < 4; kx++) {
      int ix = ix0 + kx;
      bool xok = (unsigned)ix < 128;
      float xv[4];
#pragma unroll
      for (int j = 0; j < 4; j++) {
        int lrow = 2 * (4 * rg + j) + ky;
        float v = xs[lrow * 128 + (xok ? ix : 0)];
        xv[j] = xok ? v : 0.f;
      }
      const float* wr = &wl[ky * 4 + kx][0];
#pragma unroll
      for (int c = 0; c < 16; c += 4) {
        float4 wv = *(const float4*)(wr + c);
#pragma unroll
        for (int j = 0; j < 4; j++) {
          acc[j][c + 0] = fmaf(xv[j], wv.x, acc[j][c + 0]);
          acc[j][c + 1] = fmaf(xv[j], wv.y, acc[j][c + 1]);
          acc[j][c + 2] = fmaf(xv[j], wv.z, acc[j][c + 2]);
          acc[j][c + 3] = fmaf(xv[j], wv.w, acc[j][c + 3]);
        }
      }
    }
  }

#pragma unroll
  for (int j = 0; j < 4; j++) {
    int oy = y0 + 4 * rg + j;
    float* op = out + (((size_t)n * 32 + co0) * 64 + oy) * 64 + sx;
#pragma unroll
    for (int c = 0; c < 16; c++) {
      float v = acc[j][c] + bias[co0 + c];
      op[(size_t)c * 4096] = fmaxf(v, 0.f);
    }
  }
}

// ---------------------------------------------------------------------------
// conv2: 4x4 s=2 p=1 ReLU, 64x64 -> 32x32. Baseline structure (acc[4][16],
// 4 rows x 16 co/thread, 4 blocks/sample) with PARITY-SPLIT halo tile:
// input col ix stored at row*68 + (tc&1)*34 + (tc>>1), tc = ix+1. Stride-2
// column gathers become lane-consecutive (kills the 1.5e7 bank conflicts);
// row+col halos (zeroed once) remove all bounds-selects. Values and per-
// output fmaf order (ci -> ky -> kx) identical to baseline -> bit-exact.
// ---------------------------------------------------------------------------
template<int CIN, int COUT, int CCH>
__global__ __launch_bounds__(256, 4)
void conv4x4s2_p(const float* __restrict__ x, const float* __restrict__ w,
                 const float* __restrict__ bias, float* __restrict__ out) {
  constexpr int NCH = COUT / CCH;
  int bid = blockIdx.x;
  int cchunk = bid % NCH;
  int n = bid / NCH;
  int co0 = cchunk * CCH;

  __shared__ float xs[66 * 68];   // rows 0..65 = iy+1; parity-split cols
  __shared__ float wl[16][CCH];

  int t = threadIdx.x;
  int sx = t & 31;
  int sy0 = t >> 5;

  // zero whole tile once (halos stay zero; interior overwritten per ci)
  for (int i = t; i < 66 * 68; i += 256) xs[i] = 0.f;

  float acc[4][CCH];
#pragma unroll
  for (int j = 0; j < 4; j++)
#pragma unroll
    for (int c = 0; c < CCH; c++) acc[j][c] = 0.f;

  const float* xn = x + (size_t)n * CIN * 4096;

  for (int ci = 0; ci < CIN; ci++) {
    __syncthreads();
#pragma unroll
    for (int k = 0; k < 4; k++) {
      int idx = k * 1024 + t * 4;
      int row = idx >> 6;
      int col = idx & 63;        // even
      float4 v = *(const float4*)(xn + (size_t)ci * 4096 + idx);
      float* rp = xs + (row + 1) * 68;
      int h = col >> 1;
      rp[34 + h]     = v.x;      // tc = col+1 (odd)
      rp[h + 1]      = v.y;      // tc = col+2 (even)
      rp[34 + h + 1] = v.z;      // tc = col+3 (odd)
      rp[h + 2]      = v.w;      // tc = col+4 (even)
    }
    {
      int cc = t & (CCH - 1);
      int tap = t >> 4;          // CCH==16
      if (tap < 16) wl[tap][cc] = w[(size_t)(co0 + cc) * (CIN * 16) + ci * 16 + tap];
    }
    __syncthreads();

#pragma unroll
    for (int ky = 0; ky < 4; ky++) {
#pragma unroll
      for (int kx = 0; kx < 4; kx++) {
        // tc = 2sx + kx -> phys = (kx&1)*34 + sx + (kx>>1)
        int pc = ((kx & 1) ? 34 : 0) + sx + (kx >> 1);
        float xv[4];
#pragma unroll
        for (int j = 0; j < 4; j++) {
          int row = 2 * (sy0 + j * 8) + ky;   // iy+1, in [0,65]
          xv[j] = xs[row * 68 + pc];
        }
        const float* wr = &wl[ky * 4 + kx][0];
#pragma unroll
        for (int c = 0; c < CCH; c += 4) {
          float4 wv = *(const float4*)(wr + c);
#pragma unroll
          for (int j = 0; j < 4; j++) {
            acc[j][c + 0] = fmaf(xv[j], wv.x, acc[j][c + 0]);
            acc[j][c + 1] = fmaf(xv[j], wv.y, acc[j][c + 1]);
            acc[j][c + 2] = fmaf(xv[j], wv.z, acc[j][c + 2]);
            acc[j][c + 3] = fmaf(xv[j], wv.w, acc[j][c + 3]);
          }
        }
      }
    }
  }

#pragma unroll
  for (int j = 0; j < 4; j++) {
    int sy = sy0 + j * 8;
    float* op = out + (((size_t)n * COUT + co0) * 32 + sy) * 32 + sx;
#pragma unroll
    for (int c = 0; c < CCH; c++) {
      float v = acc[j][c] + bias[co0 + c];
      v = fmaxf(v, 0.f);
      op[(size_t)c * 1024] = v;
    }
  }
}

// ---------------------------------------------------------------------------
// conv3 r8: 3x3 s=1 p=1 ReLU on 32x32, CIN=64 (ENCODER - fp32 bit-exact,
// feeds z -> argmin). 8 rows x 8 co per thread (acc[8][8] = 64 VGPR - no
// spill). Block covers 16 co via two 8-co halves x 4 rg x 32 sx = 256 thr.
// Each weight ds_read_b128 feeds 32 FMAs (2x baseline) -> per-cg weight
// b128s drop 144 -> 72. Shifted halo tile [34][34] (zeroed once) removes
// all bounds-selects. Per-output fmaf chain order (cg -> c4 -> ky -> kx)
// identical to proven baseline -> bit-exact. (256,3): VGPR budget 170.
// BEST VERIFIED: 266 us, total 1060.6 us (r6). Overlap attempts (scalar
// weights r2, reg-dbuf r7, async16 r8, async4-swizzle r9) all regressed:
// latency exposure / spill / spill / fetch amplification. Keep as-is.
// ---------------------------------------------------------------------------
template<int CIN, int COUT>
__global__ __launch_bounds__(256, 3)
void conv3x3_r8(const float* __restrict__ x, const float* __restrict__ w,
                const float* __restrict__ bias, float* __restrict__ out) {
  constexpr int NCH = COUT / 16;
  int bid = blockIdx.x;
  int cchunk = bid % NCH;
  int n = bid / NCH;
  int co0 = cchunk * 16;

  __shared__ float xs[4 * 34 * 34];
  __shared__ float wl[4 * 9][16];

  int t = threadIdx.x;
  int sx = t & 31;
  int rg = (t >> 5) & 3;   // 4 row groups x 8 rows
  int cob = (t >> 7) * 8;  // 8-co half

  // zero whole tile once (halos stay zero)
  for (int i = t; i < 4 * 34 * 34; i += 256) xs[i] = 0.f;

  float acc[8][8];
#pragma unroll
  for (int j = 0; j < 8; j++)
#pragma unroll
    for (int c = 0; c < 8; c++) acc[j][c] = 0.f;

  const float* xn = x + (size_t)n * CIN * 1024;

  for (int cg = 0; cg < CIN / 4; cg++) {
    __syncthreads();
#pragma unroll
    for (int k = 0; k < 4; k++) {
      int row = t >> 3;          // 0..31
      int col = (t & 7) * 4;     // 0..28
      float4 v = *(const float4*)(xn + (size_t)(cg * 4 + k) * 1024 + t * 4);
      float* dst = xs + k * 1156 + (row + 1) * 34 + col + 1;
      dst[0] = v.x; dst[1] = v.y; dst[2] = v.z; dst[3] = v.w;
    }
    for (int i = t; i < 4 * 9 * 16; i += 256) {
      int cc = i & 15;
      int row = i >> 4;
      int c4 = row / 9, kk = row % 9;
      wl[row][cc] = w[(size_t)(co0 + cc) * (CIN * 9) + (cg * 4 + c4) * 9 + kk];
    }
    __syncthreads();

#pragma unroll
    for (int c4 = 0; c4 < 4; c4++) {
      const float* xc = xs + c4 * 1156;
      float xv[10][3];
#pragma unroll
      for (int r = 0; r < 10; r++) {
#pragma unroll
        for (int cx = 0; cx < 3; cx++)
          xv[r][cx] = xc[(8 * rg + r) * 34 + sx + cx];  // halo handles bounds
      }
#pragma unroll
      for (int ky = 0; ky < 3; ky++) {
#pragma unroll
        for (int kx = 0; kx < 3; kx++) {
          const float* wr = &wl[c4 * 9 + ky * 3 + kx][cob];
          float4 w0 = *(const float4*)(wr);
          float4 w1 = *(const float4*)(wr + 4);
#pragma unroll
          for (int j = 0; j < 8; j++) {
            float xx = xv[j + ky][kx];
            acc[j][0] = fmaf(xx, w0.x, acc[j][0]);
            acc[j][1] = fmaf(xx, w0.y, acc[j][1]);
            acc[j][2] = fmaf(xx, w0.z, acc[j][2]);
            acc[j][3] = fmaf(xx, w0.w, acc[j][3]);
            acc[j][4] = fmaf(xx, w1.x, acc[j][4]);
            acc[j][5] = fmaf(xx, w1.y, acc[j][5]);
            acc[j][6] = fmaf(xx, w1.z, acc[j][6]);
            acc[j][7] = fmaf(xx, w1.w, acc[j][7]);
          }
        }
      }
    }
  }

#pragma unroll
  for (int j = 0; j < 8; j++) {
    int sy = 8 * rg + j;
    float* op = out + (((size_t)n * COUT + co0 + cob) * 32 + sy) * 32 + sx;
#pragma unroll
    for (int c = 0; c < 8; c++) {
      float v = acc[j][c] + bias[co0 + cob + c];
      v = fmaxf(v, 0.f);
      op[(size_t)c * 1024] = v;
    }
  }
}

// ---------------------------------------------------------------------------
// Weight prep for MFMA dect1: tw1 [ci=64][co=32][4][4] fp32 ->
// Bws bf16 [par=4][tap=4][co=32][ci=64].
// ---------------------------------------------------------------------------
__global__ void wprep_dect1(const float* __restrict__ tw1,
                            unsigned short* __restrict__ Bws) {
  int i = blockIdx.x * 256 + threadIdx.x;
  if (i < 32768) {
    int ci = i & 63;
    int co = (i >> 6) & 31;
    int tap = (i >> 11) & 3;
    int par = i >> 13;
    int py = par >> 1, px = par & 1;
    int ky0 = (py + 1) & 1, kx0 = (px + 1) & 1;
    int kyi = tap >> 1, kxi = tap & 1;
    int ky = ky0 + 2 * kyi, kx = kx0 + 2 * kxi;
    Bws[i] = f2bf(tw1[(((size_t)ci * 32 + co) * 4 + ky) * 4 + kx]);
  }
}

// ---------------------------------------------------------------------------
// Weight prep for MFMA dec1: dw1 [co=64][ci=32][3][3] fp32 ->
// Wd1 bf16 [co][tap=9][ci=32]  (row stride 288 shorts = 576B, 16B-aligned).
// ---------------------------------------------------------------------------
__global__ void wprep_dec1(const float* __restrict__ dw1,
                           unsigned short* __restrict__ Wd1) {
  int i = blockIdx.x * 256 + threadIdx.x;
  if (i < 18432) {
    int ci = i & 31;
    int tap = (i >> 5) % 9;
    int co = i / 288;
    Wd1[i] = f2bf(dw1[(size_t)(co * 32 + ci) * 9 + tap]);
  }
}

// ---------------------------------------------------------------------------
// dec1 via MFMA (bf16 in, fp32 acc): 3x3 s=1 p=1 ReLU,
// qz [smp][32ci][32][32] fp32 -> d1 [smp][64co][32][32] fp32.
// ---------------------------------------------------------------------------
__global__ __launch_bounds__(256, 4)
void dec1_mfma(const float* __restrict__ qz,
               const unsigned short* __restrict__ Wd1,
               const float* __restrict__ bias, float* __restrict__ d1) {
  int strip = blockIdx.x & 3;
  int smp = blockIdx.x >> 2;
  int y0 = strip * 8;

  __shared__ __align__(16) unsigned short xt[10 * 34 * 32];

  int t = threadIdx.x;
  // stage rows y0-1..y0+8, cols -1..32, 32 ci (bf16 pairs)
  for (int idx = t; idx < 16 * 10 * 34; idx += 256) {
    int cc = idx % 34;
    int tmp = idx / 34;
    int rr = tmp % 10;
    int pp = tmp / 10;                 // ci pair 0..15
    int gy = y0 - 1 + rr;
    int gx = cc - 1;
    bool ok = ((unsigned)gy < 32) && ((unsigned)gx < 32);
    const float* p = qz + ((size_t)smp * 32 + 2 * pp) * 1024 + gy * 32 + gx;
    float v0 = ok ? p[0] : 0.f;
    float v1 = ok ? p[1024] : 0.f;
    unsigned pk = (unsigned)f2bf(v0) | ((unsigned)f2bf(v1) << 16);
    *(unsigned*)(&xt[(rr * 34 + cc) * 32 + 2 * pp]) = pk;
  }

  int lane = t & 63;
  int wv = t >> 6;                    // co-tile 0..3
  int mlo = lane & 15;
  int khi = lane >> 4;

  // A-frags: weights for co = wv*16+mlo, all 9 taps (global, L2-hot)
  short8 afr[9];
#pragma unroll
  for (int tap = 0; tap < 9; tap++)
    afr[tap] = *(const short8*)(Wd1 + (size_t)(wv * 16 + mlo) * 288 +
                                tap * 32 + khi * 8);
  float bb[4];
#pragma unroll
  for (int r = 0; r < 4; r++) bb[r] = bias[wv * 16 + khi * 4 + r];

  __syncthreads();

  for (int pt = 0; pt < 16; pt++) {
    int rl = pt >> 1;                 // row in strip 0..7
    int chf = pt & 1;                 // col half
    f32x4 acc = {0.f, 0.f, 0.f, 0.f};
#pragma unroll
    for (int tap = 0; tap < 9; tap++) {
      int ky = tap / 3, kx = tap % 3;
      const unsigned short* bp =
          xt + (((rl + ky) * 34) + chf * 16 + mlo + kx) * 32 + khi * 8;
      short8 b = *(const short8*)bp;
      acc = __builtin_amdgcn_mfma_f32_16x16x32_bf16(afr[tap], b, acc, 0, 0, 0);
    }
    int gyo = y0 + rl;
    int gxo = chf * 16 + mlo;
#pragma unroll
    for (int r = 0; r < 4; r++) {
      int co = wv * 16 + khi * 4 + r;
      d1[(((size_t)smp * 64 + co) * 32 + gyo) * 32 + gxo] =
          fmaxf(acc[r] + bb[r], 0.f);
    }
  }
}

// ---------------------------------------------------------------------------
// dect1 via MFMA: tconv k=4 s=2 p=1 ReLU,
// d1 [smp][64ci][32][32] fp32 -> d2 [smp][32co][64][64] fp32.
// ---------------------------------------------------------------------------
__global__ __launch_bounds__(256, 4)
void convt_mfma(const float* __restrict__ d1,
                const unsigned short* __restrict__ Bws,
                const float* __restrict__ bias, float* __restrict__ d2) {
  constexpr int CP = 72;
  int bid = blockIdx.x;
  int rp = bid & 15;
  int smp = bid >> 4;

  __shared__ __align__(16) unsigned short xt[4 * 34 * CP];

  int t = threadIdx.x;

  for (int idx = t; idx < 32 * 4 * 34; idx += 256) {
    int cc = idx % 34;
    int tmp = idx / 34;
    int rr = tmp & 3;
    int pp = tmp >> 2;
    int gy = 2 * rp - 1 + rr;
    int gx = cc - 1;
    bool ok = ((unsigned)gy < 32) && ((unsigned)gx < 32);
    const float* p = d1 + ((size_t)smp * 64 + 2 * pp) * 1024 + gy * 32 + gx;
    float v0 = ok ? p[0] : 0.f;
    float v1 = ok ? p[1024] : 0.f;
    unsigned pk = (unsigned)f2bf(v0) | ((unsigned)f2bf(v1) << 16);
    *(unsigned*)(&xt[(rr * 34 + cc) * CP + 2 * pp]) = pk;
  }
  __syncthreads();

  int lane = t & 63;
  int wv = t >> 6;
  int row2 = wv >> 1;
  int c0 = (wv & 1) * 16;
  int mlo = lane & 15;
  int khi = lane >> 4;

  f32x4 acc[4][2];
#pragma unroll
  for (int par = 0; par < 4; par++)
#pragma unroll
    for (int nt = 0; nt < 2; nt++) {
      f32x4 z = {0.f, 0.f, 0.f, 0.f};
      acc[par][nt] = z;
    }

#pragma unroll
  for (int par = 0; par < 4; par++) {
    int py = par >> 1, px = par & 1;
    int ky0 = (py + 1) & 1, kx0 = (px + 1) & 1;
    int ay = (py + 1 - ky0) >> 1;
    int ax = (px + 1 - kx0) >> 1;
#pragma unroll
    for (int tap = 0; tap < 4; tap++) {
      int kyi = tap >> 1, kxi = tap & 1;
      int rrp = row2 + 1 + (ay - kyi);
      int ccb = c0 + 1 + (ax - kxi);
#pragma unroll
      for (int kc = 0; kc < 2; kc++) {
        const unsigned short* ap =
            xt + ((rrp * 34) + ccb + mlo) * CP + kc * 32 + khi * 8;
        short8 a = *(const short8*)ap;
#pragma unroll
        for (int nt = 0; nt < 2; nt++) {
          const unsigned short* bp =
              Bws + (((size_t)(par * 4 + tap) * 32 + nt * 16 + mlo) * 64) +
              kc * 32 + khi * 8;
          short8 b = *(const short8*)bp;
          acc[par][nt] =
              __builtin_amdgcn_mfma_f32_16x16x32_bf16(a, b, acc[par][nt], 0, 0, 0);
        }
      }
    }
  }

  int sy = 2 * rp + row2;
#pragma unroll
  for (int par = 0; par < 4; par++) {
    int py = par >> 1, px = par & 1;
    int oy = 2 * sy + py;
#pragma unroll
    for (int nt = 0; nt < 2; nt++) {
      int co = nt * 16 + mlo;
      float b = bias[co];
      float* op = d2 + (((size_t)smp * 32 + co) * 64 + oy) * 64;
#pragma unroll
      for (int r = 0; r < 4; r++) {
        int sx = c0 + khi * 4 + r;
        int ox = 2 * sx + px;
        op[ox] = fmaxf(acc[par][nt][r] + b, 0.f);
      }
    }
  }
}

// ---------------------------------------------------------------------------
// dect2: tconv k=4 s=2 p=1, CIN=32, COUT=1, sigmoid; all 4 parities per
// thread. CSTG=8. grid = NB * 4 row-tiles. 64x64 -> 128x128.
// ---------------------------------------------------------------------------
__global__ __launch_bounds__(256, 4)
void dect2_full(const float* __restrict__ x, const float* __restrict__ w,
                const float* __restrict__ bias, float* __restrict__ out) {
  int ptile = blockIdx.x & 3;
  int n = blockIdx.x >> 2;
  int y0 = ptile * 16;

  __shared__ float xs[8][1152];
  int t = threadIdx.x;
  int sx = t & 63;
  int r4 = t >> 6;

  float acc[4][4];
#pragma unroll
  for (int j = 0; j < 4; j++)
#pragma unroll
    for (int p = 0; p < 4; p++) acc[j][p] = 0.f;

  const float* xn = x + (size_t)n * 32 * 4096;

  for (int cg = 0; cg < 4; cg++) {
    __syncthreads();
    for (int idx = t; idx < 8 * 1152; idx += 256) {
      int ch = idx / 1152;
      int rem = idx % 1152;
      int iy = y0 - 1 + rem / 64;
      int ix = rem & 63;
      bool ok = (unsigned)iy < 64;
      xs[ch][rem] = ok ? xn[(size_t)(cg * 8 + ch) * 4096 + iy * 64 + ix] : 0.f;
    }
    __syncthreads();

#pragma unroll
    for (int c4 = 0; c4 < 8; c4++) {
      int ci = cg * 8 + c4;
      const float* xc = &xs[c4][0];
      float xv[6][3];
#pragma unroll
      for (int r = 0; r < 6; r++) {
        int srow = 4 * r4 + r;
#pragma unroll
        for (int cx = 0; cx < 3; cx++) {
          int ix = sx - 1 + cx;
          bool ok = (unsigned)ix < 64;
          float v = xc[ok ? srow * 64 + ix : 0];
          xv[r][cx] = ok ? v : 0.f;
        }
      }
      float w16[16];
#pragma unroll
      for (int q = 0; q < 4; q++) {
        float4 ww = *(const float4*)(w + ci * 16 + 4 * q);
        w16[4 * q + 0] = ww.x; w16[4 * q + 1] = ww.y;
        w16[4 * q + 2] = ww.z; w16[4 * q + 3] = ww.w;
      }
#pragma unroll
      for (int py = 0; py < 2; py++) {
#pragma unroll
        for (int px = 0; px < 2; px++) {
          int par = py * 2 + px;
          int ky0 = (py + 1) & 1, kx0 = (px + 1) & 1;
          int ay = (py + 1 - ky0) >> 1;
          int ax = (px + 1 - kx0) >> 1;
#pragma unroll
          for (int kyi = 0; kyi < 2; kyi++) {
#pragma unroll
            for (int kxi = 0; kxi < 2; kxi++) {
              float wv = w16[(ky0 + 2 * kyi) * 4 + (kx0 + 2 * kxi)];
#pragma unroll
              for (int j = 0; j < 4; j++) {
                float xx = xv[j + ay + 1 - kyi][ax + 1 - kxi];
                acc[j][par] = fmaf(xx, wv, acc[j][par]);
              }
            }
          }
        }
      }
    }
  }

  float b0 = bias[0];
#pragma unroll
  for (int j = 0; j < 4; j++) {
    int iy = y0 + 4 * r4 + j;
#pragma unroll
    for (int py = 0; py < 2; py++) {
      float v0 = acc[j][py * 2 + 0] + b0;
      float v1 = acc[j][py * 2 + 1] + b0;
      float2 o;
      o.x = 1.f / (1.f + expf(-v0));
      o.y = 1.f / (1.f + expf(-v1));
      int oy = 2 * iy + py;
      *(float2*)(out + (size_t)n * 16384 + oy * 128 + 2 * sx) = o;
    }
  }
}

// ---------------------------------------------------------------------------
__global__ void cbn_prep(const float* __restrict__ cb, float* __restrict__ cbn) {
#pragma clang fp contract(off)
  int k = blockIdx.x * 256 + threadIdx.x;
  if (k < 512) {
    float m[32];
#pragma unroll
    for (int d = 0; d < 32; d++) {
      float c = cb[k * 32 + d];
      m[d] = c * c;
    }
    float r[8];
#pragma unroll
    for (int j = 0; j < 8; j++)
      r[j] = ((m[j] + m[8 + j]) + m[16 + j]) + m[24 + j];
    cbn[k] = ((r[0] + r[1]) + (r[2] + r[3])) + ((r[4] + r[5]) + (r[6] + r[7]));
  }
}

// ---------------------------------------------------------------------------
// FUSED conv4 (1x1) + VQ (np-exact arithmetic; proven).
// ---------------------------------------------------------------------------
__global__ __launch_bounds__(256)
void vq_fused(const float* __restrict__ h3, const float* __restrict__ w4,
              const float* __restrict__ b4, const float* __restrict__ cb,
              const float* __restrict__ cbn, float* __restrict__ qz,
              float* __restrict__ loss) {
  __shared__ float wl[64][32];
  int tid = threadIdx.x;
  for (int i = tid; i < 2048; i += 256) {
    int co = i & 31;
    int ci = i >> 5;
    wl[ci][co] = w4[(size_t)co * 64 + ci];
  }
  __syncthreads();

  int n = blockIdx.x >> 2;
  int p = (blockIdx.x & 3) * 256 + tid;
  const float* hn = h3 + (size_t)n * 65536;

  float zv[32];
#pragma unroll
  for (int c = 0; c < 32; c++) zv[c] = 0.f;
  for (int ci = 0; ci < 64; ci++) {
    float xv = hn[(size_t)ci * 1024 + p];
#pragma unroll
    for (int c = 0; c < 32; c += 4) {
      float4 wv = *(const float4*)&wl[ci][c];
      zv[c + 0] = fmaf(xv, wv.x, zv[c + 0]);
      zv[c + 1] = fmaf(xv, wv.y, zv[c + 1]);
      zv[c + 2] = fmaf(xv, wv.z, zv[c + 2]);
      zv[c + 3] = fmaf(xv, wv.w, zv[c + 3]);
    }
  }
#pragma unroll
  for (int c = 0; c < 32; c++) zv[c] = zv[c] + b4[c];

  float zz;
  {
#pragma clang fp contract(off)
    float m[32];
#pragma unroll
    for (int d = 0; d < 32; d++) m[d] = zv[d] * zv[d];
    float r[8];
#pragma unroll
    for (int j = 0; j < 8; j++)
      r[j] = ((m[j] + m[8 + j]) + m[16 + j]) + m[24 + j];
    zz = ((r[0] + r[1]) + (r[2] + r[3])) + ((r[4] + r[5]) + (r[6] + r[7]));
  }

  float best = 3.4e38f;
  int bk = 0;
  for (int k4 = 0; k4 < 512; k4 += 4) {
    float4 cn = *(const float4*)(cbn + k4);
    float da[4];
#pragma unroll
    for (int u = 0; u < 4; u++) da[u] = 0.f;
#pragma unroll
    for (int d = 0; d < 32; d += 4) {
#pragma unroll
      for (int u = 0; u < 4; u++) {
        float4 c = *(const float4*)(cb + (size_t)(k4 + u) * 32 + d);
        float a = da[u];
        a = fmaf(zv[d + 0], c.x, a);
        a = fmaf(zv[d + 1], c.y, a);
        a = fmaf(zv[d + 2], c.z, a);
        a = fmaf(zv[d + 3], c.w, a);
        da[u] = a;
      }
    }
#pragma unroll
    for (int u = 0; u < 4; u++) {
      float cnu = (u == 0) ? cn.x : (u == 1) ? cn.y : (u == 2) ? cn.z : cn.w;
      float s;
      {
#pragma clang fp contract(off)
        s = (zz + cnu) - 2.f * da[u];
      }
      int k = k4 + u;
      if (s < best) { best = s; bk = k; }
    }
  }

  float lsum = 0.f;
  float* qn = qz + (size_t)n * 32768;
#pragma unroll
  for (int d = 0; d < 32; d += 4) {
#pragma clang fp contract(off)
    float4 q = *(const float4*)(cb + (size_t)bk * 32 + d);
    float e;
    e = q.x - zv[d + 0]; lsum = fmaf(e, e, lsum);
    e = q.y - zv[d + 1]; lsum = fmaf(e, e, lsum);
    e = q.z - zv[d + 2]; lsum = fmaf(e, e, lsum);
    e = q.w - zv[d + 3]; lsum = fmaf(e, e, lsum);
    qn[(size_t)(d + 0) * 1024 + p] = zv[d + 0] + (q.x - zv[d + 0]);
    qn[(size_t)(d + 1) * 1024 + p] = zv[d + 1] + (q.y - zv[d + 1]);
    qn[(size_t)(d + 2) * 1024 + p] = zv[d + 2] + (q.z - zv[d + 2]);
    qn[(size_t)(d + 3) * 1024 + p] = zv[d + 3] + (q.w - zv[d + 3]);
  }

#pragma unroll
  for (int off = 32; off; off >>= 1) lsum += __shfl_down(lsum, off, 64);
  if ((tid & 63) == 0) atomicAdd(loss, lsum);
}

__global__ void finalize_loss(const float* __restrict__ loss, float* __restrict__ out) {
  if (threadIdx.x == 0) {
    float m = loss[0] / 8388608.f;
    out[0] = m + 0.26f * m;
  }
}

// ---------------------------------------------------------------------------
// Workspace (floats): A = chunk*131072, B = chunk*65536, cbn 512, loss 1,
// pad 3, Bws 32768 shorts (16384 fl), Wd1 18432 shorts (9216 fl).
// ---------------------------------------------------------------------------
extern "C" void kernel_launch(void* const* d_in, const int* in_sizes, int n_in,
                              void* d_out, int out_size, void* d_ws, size_t ws_size,
                              hipStream_t stream) {
  (void)in_sizes; (void)n_in; (void)out_size;
  const float* x   = (const float*)d_in[0];
  const float* ew1 = (const float*)d_in[1];
  const float* eb1 = (const float*)d_in[2];
  const float* ew2 = (const float*)d_in[3];
  const float* eb2 = (const float*)d_in[4];
  const float* ew3 = (const float*)d_in[5];
  const float* eb3 = (const float*)d_in[6];
  const float* ew4 = (const float*)d_in[7];
  const float* eb4 = (const float*)d_in[8];
  const float* cb  = (const float*)d_in[9];
  const float* dw1 = (const float*)d_in[10];
  const float* db1 = (const float*)d_in[11];
  const float* tw1 = (const float*)d_in[12];
  const float* tb1 = (const float*)d_in[13];
  const float* tw2 = (const float*)d_in[14];
  const float* tb2 = (const float*)d_in[15];
  float* out = (float*)d_out;

  auto need = [](size_t c) -> size_t {
    return (c * 196608 + 516 + 16384 + 9216) * 4;
  };
  int nchunks = 4;
  if (ws_size >= need(256)) nchunks = 1;
  else if (ws_size >= need(128)) nchunks = 2;
  int chunk = 256 / nchunks;

  float* ws = (float*)d_ws;
  float* A = ws;
  float* B = A + (size_t)chunk * 131072;
  float* cbn = B + (size_t)chunk * 65536;
  float* lossacc = cbn + 512;
  unsigned short* Bws = (unsigned short*)(cbn + 516);          // 16B-aligned
  unsigned short* Wd1 = (unsigned short*)(cbn + 516 + 16384);  // 16B-aligned

  float* h1 = A;
  float* h2 = B;
  float* h3 = A;
  float* qz = A + (size_t)chunk * 98304;
  float* d1 = B;
  float* d2 = A;

  cbn_prep<<<2, 256, 0, stream>>>(cb, cbn);
  wprep_dect1<<<128, 256, 0, stream>>>(tw1, Bws);
  wprep_dec1<<<72, 256, 0, stream>>>(dw1, Wd1);
  (void)hipMemsetAsync(lossacc, 0, 4, stream);

  for (int c = 0; c < nchunks; c++) {
    const float* xc = x + (size_t)c * chunk * 128 * 128;
    float* outc = out + (size_t)c * chunk * 128 * 128;

    conv1_lds<<<chunk * 8, 256, 0, stream>>>(xc, ew1, eb1, h1);
    conv4x4s2_p<32, 64, 16>
        <<<chunk * 4, 256, 0, stream>>>(h1, ew2, eb2, h2);
    conv3x3_r8<64, 64>
        <<<chunk * 4, 256, 0, stream>>>(h2, ew3, eb3, h3);

    vq_fused<<<chunk * 4, 256, 0, stream>>>(h3, ew4, eb4, cb, cbn, qz, lossacc);

    dec1_mfma<<<chunk * 4, 256, 0, stream>>>(qz, Wd1, db1, d1);
    convt_mfma<<<chunk * 16, 256, 0, stream>>>(d1, Bws, tb1, d2);
    dect2_full<<<chunk * 4, 256, 0, stream>>>(d2, tw2, tb2, outc);
  }

  finalize_loss<<<1, 64, 0, stream>>>(lossacc, out + 4194304);
}